// Round 12
// baseline (705.847 us; speedup 1.0000x reference)
//
#include <hip/hip_runtime.h>

// EncoderALSTM: T=128, B=32, H=256, I=256, 4H=1024.
// Round-12 = Round-11 resubmitted (R11 bench died in harness infra, no test
// output). Structure = Round-8 recurrent (best measured: 457 us) with:
//  - compute_gih kernel DELETED: gih computed just-in-time in the F phase
//    (W_ih slice register-resident, emb_t staged to LDS by idle wave 6
//    during the poll phase; bias in a register).
//  - clamp-softmax (no max pass; validated in R10 at absmax 0.0039).
//  - R9 (ctr gate) and R10 (fused Z, redundant cell) reverted.
//
// ws layout (bytes):
//   Whh_pack @0         524,288  uint4 [m][512 thr][8]
//   Wih_pack @524288    524,288  uint4 [m][512 thr][8]
//   Wa_pack  @1048576   262,144  uint4 [m][256 j][8] (c<4 ctx, c>=4 h cols)
//   ywp      @1310720   524,288  u64 [32 b][8 m][256 j] tagged {y,w} partials
//   psx      @1835008   131,072  u64 [32 b][8 m][64]    tagged score pairs

#define T_DIM 128
#define B_DIM 32

typedef _Float16 half2_t __attribute__((ext_vector_type(2)));

static __device__ __forceinline__ unsigned pack2(float a, float b) {
  half2_t h;
  h.x = (_Float16)a;
  h.y = (_Float16)b;
  return __builtin_bit_cast(unsigned, h);
}

static __device__ __forceinline__ float dot2f(unsigned w, unsigned v, float acc) {
  half2_t a = __builtin_bit_cast(half2_t, w);
  half2_t b = __builtin_bit_cast(half2_t, v);
#if __has_builtin(__builtin_amdgcn_fdot2)
  return __builtin_amdgcn_fdot2(a, b, acc, false);
#else
  return acc + (float)a.x * (float)b.x + (float)a.y * (float)b.y;
#endif
}

static __device__ __forceinline__ float dot8(uint4 w, uint4 v, float acc) {
  acc = dot2f(w.x, v.x, acc);
  acc = dot2f(w.y, v.y, acc);
  acc = dot2f(w.z, v.z, acc);
  acc = dot2f(w.w, v.w, acc);
  return acc;
}

static __device__ __forceinline__ float lo16(unsigned u) {
  return (float)__builtin_bit_cast(half2_t, u).x;
}
static __device__ __forceinline__ float hi16(unsigned u) {
  return (float)__builtin_bit_cast(half2_t, u).y;
}

static __device__ __forceinline__ float fsig(float x) {
  return __builtin_amdgcn_rcpf(1.f + __expf(-x));
}
static __device__ __forceinline__ float ftanh(float x) {
  float e = __expf(2.f * x);
  return 1.f - 2.f * __builtin_amdgcn_rcpf(e + 1.f);
}

static __device__ __forceinline__ unsigned long long wait_word(
    const unsigned long long* p, unsigned want, unsigned long long v) {
  while ((unsigned)v != want) {
    __builtin_amdgcn_s_sleep(1);
    v = __hip_atomic_load(p, __ATOMIC_RELAXED, __HIP_MEMORY_SCOPE_AGENT);
  }
  return v;
}

// ---------------- kernel 0: pack weights + zero tag buffers ----------------
__global__ void pack_weights(const float* __restrict__ W_ih, const float* __restrict__ W_hh,
                             const float* __restrict__ W_a, uint4* __restrict__ Whh_pack,
                             uint4* __restrict__ Wih_pack, uint4* __restrict__ Wa_pack,
                             unsigned long long* __restrict__ ywp,
                             unsigned long long* __restrict__ psx) {
  int n = blockIdx.x * 256 + threadIdx.x;  // 0..65535
  if (n < 32768) {  // Whh_pack[m][tid][i] and Wih_pack[m][tid][i]: W[r][(4i+qk)*8 ..+8]
    int m = n >> 12, tid = (n >> 3) & 511, i = n & 7;
    int r_local = tid >> 2, qk = tid & 3;
    int q = r_local >> 5, jl = r_local & 31;
    int r = q * 256 + m * 32 + jl;
    {
      const float* src = W_hh + r * 256 + (4 * i + qk) * 8;
      uint4 v;
      v.x = pack2(src[0], src[1]);
      v.y = pack2(src[2], src[3]);
      v.z = pack2(src[4], src[5]);
      v.w = pack2(src[6], src[7]);
      Whh_pack[n] = v;
    }
    {
      const float* src = W_ih + r * 256 + (4 * i + qk) * 8;
      uint4 v;
      v.x = pack2(src[0], src[1]);
      v.y = pack2(src[2], src[3]);
      v.z = pack2(src[4], src[5]);
      v.w = pack2(src[6], src[7]);
      Wih_pack[n] = v;
    }
  }
  if (n < 16384) {  // Wa_pack[m][j][c]: c<4 ctx col m*32+c*8; c>=4 h col 256+m*32+(c-4)*8
    int m = n >> 11, j = (n >> 3) & 255, c = n & 7;
    int col0 = (c < 4) ? (m * 32 + c * 8) : (256 + m * 32 + (c - 4) * 8);
    const float* src = W_a + j * 512 + col0;
    uint4 v;
    v.x = pack2(src[0], src[1]);
    v.y = pack2(src[2], src[3]);
    v.z = pack2(src[4], src[5]);
    v.w = pack2(src[6], src[7]);
    Wa_pack[n] = v;
  }
  __hip_atomic_store(&ywp[n], 0ull, __ATOMIC_RELAXED, __HIP_MEMORY_SCOPE_AGENT);
  if (n < 16384)
    __hip_atomic_store(&psx[n], 0ull, __ATOMIC_RELAXED, __HIP_MEMORY_SCOPE_AGENT);
}

// ---------------- kernel 1: recurrent (JIT gih) ----------------
__global__ void __launch_bounds__(512, 1)
alstm_rec(const int* __restrict__ lens, const float* __restrict__ embs,
          const uint4* __restrict__ Whh_pack, const uint4* __restrict__ Wih_pack,
          const uint4* __restrict__ Wa_pack, const float* __restrict__ b_ih,
          const float* __restrict__ b_hh, const float* __restrict__ b_a,
          unsigned long long* __restrict__ ywp, unsigned long long* __restrict__ psx,
          float* __restrict__ out, float* __restrict__ hfin, float* __restrict__ cfin) {
  const int tid = threadIdx.x;  // 512 threads = 8 waves
  const int b = blockIdx.x & 31;
  const int m = blockIdx.x >> 5;
  const int wv = tid >> 6, lane = tid & 63;

  __shared__ __align__(16) unsigned histSl[128 * 20];  // own h slice history (stride 20)
  __shared__ __align__(16) float ystoreF[128 * 256];   // y history f32, 128 KB
  __shared__ __align__(16) unsigned hp2[128];          // h' pairs
  __shared__ __align__(16) unsigned hsl2[16];          // own h_t slice pairs
  __shared__ __align__(16) unsigned ebuf[128];         // emb_t f16 pairs
  __shared__ float sc[128];                            // scores -> alpha
  __shared__ float zp[4][256];                         // z partials
  __shared__ float gsl[128];

  // ---- register-resident weights ----
  uint4 wh4[8], wi4[8];
  {
    const uint4* p = Whh_pack + ((size_t)m * 512 + tid) * 8;
#pragma unroll
    for (int i = 0; i < 8; ++i) wh4[i] = p[i];
  }
  {
    const uint4* p = Wih_pack + ((size_t)m * 512 + tid) * 8;
#pragma unroll
    for (int i = 0; i < 8; ++i) wi4[i] = p[i];
  }
  uint4 way[4], waw[4];  // W_a slice cols for publish row j_pub = (tid-128)&255
  {
    const int j_pub = (tid - 128) & 255;
    const uint4* p = Wa_pack + ((size_t)m * 256 + j_pub) * 8;
#pragma unroll
    for (int i = 0; i < 4; ++i) way[i] = p[i];
#pragma unroll
    for (int i = 0; i < 4; ++i) waw[i] = p[4 + i];
  }
  const float ba_j = (tid < 256) ? b_a[tid] : 0.f;
  const int len_b = lens[b];
  const int r_local = tid >> 2, qk = tid & 3;
  const int gq = r_local >> 5, gjl = r_local & 31;
  const int grow = gq * 256 + m * 32 + gjl;  // global gate row
  const float bias_r = b_ih[grow] + b_hh[grow];

  if (tid < 128) hp2[tid] = 0u;
  // prologue: stage emb[0]
  if (tid < 64) {
    float4 e = *(const float4*)(embs + ((size_t)0 * 32 + b) * 256 + 4 * tid);
    ebuf[2 * tid] = pack2(e.x, e.y);
    ebuf[2 * tid + 1] = pack2(e.z, e.w);
  }
  float c_reg = 0.f;  // lanes tid<32
  __syncthreads();

  for (int t = 0; t < T_DIM; ++t) {
    float w_j = 0.f;

    if (t > 0) {
      // ---- poll: ywp (waves 0-3) || psx + fused clamp-softmax (wave 7)
      //      || emb_t staging (wave 6) ----
      if (tid < 256) {
        const unsigned long long* base = ywp + b * 2048 + tid;
        unsigned long long v[8];
#pragma unroll
        for (int mm = 0; mm < 8; ++mm)
          v[mm] = __hip_atomic_load(base + mm * 256, __ATOMIC_RELAXED, __HIP_MEMORY_SCOPE_AGENT);
#pragma unroll
        for (int mm = 0; mm < 8; ++mm) v[mm] = wait_word(base + mm * 256, (unsigned)t, v[mm]);
        float y = 0.f, w = 0.f;
#pragma unroll
        for (int mm = 0; mm < 8; ++mm) {
          unsigned pl = (unsigned)(v[mm] >> 32);
          y += lo16(pl);
          w += hi16(pl);
        }
        w_j = w;
        ystoreF[(t - 1) * 256 + tid] = y;
      } else if (wv == 6) {
        if (lane < 64) {
          float4 e = *(const float4*)(embs + ((size_t)t * 32 + b) * 256 + 4 * lane);
          ebuf[2 * lane] = pack2(e.x, e.y);
          ebuf[2 * lane + 1] = pack2(e.z, e.w);
        }
      } else if (wv == 7) {
        const unsigned long long* base = psx + b * 512 + lane;
        unsigned long long v[8];
#pragma unroll
        for (int mm = 0; mm < 8; ++mm)
          v[mm] = __hip_atomic_load(base + mm * 64, __ATOMIC_RELAXED, __HIP_MEMORY_SCOPE_AGENT);
#pragma unroll
        for (int mm = 0; mm < 8; ++mm) v[mm] = wait_word(base + mm * 64, (unsigned)t, v[mm]);
        float s0 = 0.f, s1 = 0.f;
#pragma unroll
        for (int mm = 0; mm < 8; ++mm) {
          unsigned pl = (unsigned)(v[mm] >> 32);
          s0 += lo16(pl);
          s1 += hi16(pl);
        }
        // clamp-softmax (no max pass; exact here, overflow-safe)
        float e0 = (2 * lane < t) ? __expf(fminf(s0, 60.f)) : 0.f;
        float e1 = (2 * lane + 1 < t) ? __expf(fminf(s1, 60.f)) : 0.f;
        float sm = e0 + e1;
#pragma unroll
        for (int off = 32; off >= 1; off >>= 1) sm += __shfl_xor(sm, off);
        float inv = __builtin_amdgcn_rcpf(sm);
        sc[2 * lane] = e0 * inv;
        sc[2 * lane + 1] = e1 * inv;
      }
      __syncthreads();
      // ---- Z: z partials over f32 y-history (4-way split, independent accums) ----
      {
        const int sp = tid >> 7, p2 = tid & 127;
        float c0 = 0.f, c1 = 0.f;
        const float* yb = ystoreF + 2 * p2;
        for (int s = sp; s < t; s += 4) {
          float al = sc[s];
          float2 yv = *(const float2*)(yb + s * 256);
          c0 += al * yv.x;
          c1 += al * yv.y;
        }
        zp[sp][2 * p2] = c0;
        zp[sp][2 * p2 + 1] = c1;
      }
      __syncthreads();
      // ---- H': h'_j = tanh(ba + w + z) ----
      if (tid < 256) {
        float z = zp[0][tid] + zp[1][tid] + zp[2][tid] + zp[3][tid];
        float hv = ftanh(ba_j + w_j + z);
        float o = __shfl_xor(hv, 1);
        if (!(tid & 1)) hp2[tid >> 1] = pack2(hv, o);
      }
      __syncthreads();
    }
    // ---- F: gates row r_local = W_ih.emb + W_hh.h' + bias, chunks c==qk (mod 4) ----
    {
      float a = 0.f, a2 = 0.f;
#pragma unroll
      for (int i = 0; i < 8; ++i) {
        const int c = 4 * i + qk;
        uint4 hv = *(const uint4*)&hp2[c << 2];
        a = dot8(wh4[i], hv, a);
        uint4 ev = *(const uint4*)&ebuf[c << 2];
        a2 = dot8(wi4[i], ev, a2);
      }
      a += a2;
      a += __shfl_xor(a, 1);
      a += __shfl_xor(a, 2);
      if (qk == 0) gsl[r_local] = a + bias_r;
    }
    __syncthreads();
    // ---- cell + score-partial publish (wave 0, in-wave LDS handoff) ----
    if (tid < 64) {
      if (tid < 32) {
        float ig = fsig(gsl[tid]);
        float fg = fsig(gsl[32 + tid]);
        float gg = ftanh(gsl[64 + tid]);
        float og = fsig(gsl[96 + tid]);
        float cn = fg * c_reg + ig * gg;
        float hn = og * ftanh(cn);
        c_reg = cn;
        out[((size_t)t * 32 + b) * 256 + m * 32 + tid] = hn;
        if (t == len_b - 1) {
          hfin[b * 256 + m * 32 + tid] = hn;
          cfin[b * 256 + m * 32 + tid] = cn;
        }
        float o = __shfl_xor(hn, 1);
        if (!(tid & 1)) {
          unsigned u = pack2(hn, o);
          hsl2[tid >> 1] = u;
          histSl[t * 20 + (tid >> 1)] = u;
        }
      }
      uint4 q0 = *(const uint4*)&hsl2[0];
      uint4 q1 = *(const uint4*)&hsl2[4];
      uint4 q2 = *(const uint4*)&hsl2[8];
      uint4 q3 = *(const uint4*)&hsl2[12];
      const int r0 = 2 * tid, r1 = 2 * tid + 1;
      float a0 = 0.f, a1 = 0.f;
      {
        uint4 h0, h1;
        h0 = *(const uint4*)&histSl[r0 * 20 + 0];
        h1 = *(const uint4*)&histSl[r1 * 20 + 0];
        a0 = dot8(h0, q0, a0);
        a1 = dot8(h1, q0, a1);
        h0 = *(const uint4*)&histSl[r0 * 20 + 4];
        h1 = *(const uint4*)&histSl[r1 * 20 + 4];
        a0 = dot8(h0, q1, a0);
        a1 = dot8(h1, q1, a1);
        h0 = *(const uint4*)&histSl[r0 * 20 + 8];
        h1 = *(const uint4*)&histSl[r1 * 20 + 8];
        a0 = dot8(h0, q2, a0);
        a1 = dot8(h1, q2, a1);
        h0 = *(const uint4*)&histSl[r0 * 20 + 12];
        h1 = *(const uint4*)&histSl[r1 * 20 + 12];
        a0 = dot8(h0, q3, a0);
        a1 = dot8(h1, q3, a1);
      }
      unsigned long long v = ((unsigned long long)pack2(a0, a1) << 32) |
                             (unsigned long long)(unsigned)(t + 1);
      __hip_atomic_store(&psx[b * 512 + m * 64 + tid], v, __ATOMIC_RELAXED,
                         __HIP_MEMORY_SCOPE_AGENT);
    }
    __syncthreads();
    // ---- y/w partial publish (tid 128..383) ----
    if (tid >= 128 && tid < 384) {
      const int j = tid - 128;
      float ay = 0.f, aw = 0.f;
#pragma unroll
      for (int c = 0; c < 4; ++c) {
        uint4 hv = *(const uint4*)&hsl2[c * 4];
        ay = dot8(way[c], hv, ay);
        aw = dot8(waw[c], hv, aw);
      }
      unsigned long long v = ((unsigned long long)pack2(ay, aw) << 32) |
                             (unsigned long long)(unsigned)(t + 1);
      __hip_atomic_store(&ywp[b * 2048 + m * 256 + j], v, __ATOMIC_RELAXED,
                         __HIP_MEMORY_SCOPE_AGENT);
    }
    // no barrier at loop wrap: next poll reads global tags; LDS hazards are
    // separated by the next iteration's barriers
  }
}

extern "C" void kernel_launch(void* const* d_in, const int* in_sizes, int n_in,
                              void* d_out, int out_size, void* d_ws, size_t ws_size,
                              hipStream_t stream) {
  const float* embs = (const float*)d_in[0];
  const int* lens = (const int*)d_in[1];
  const float* W_ih = (const float*)d_in[2];
  const float* W_hh = (const float*)d_in[3];
  const float* b_ih = (const float*)d_in[4];
  const float* b_hh = (const float*)d_in[5];
  const float* W_a = (const float*)d_in[6];
  const float* b_a = (const float*)d_in[7];

  float* out = (float*)d_out;                       // [T,B,H]
  float* hfin = out + (size_t)T_DIM * B_DIM * 256;  // [B,H]
  float* cfin = hfin + (size_t)B_DIM * 256;         // [B,H]

  char* ws = (char*)d_ws;
  uint4* Whh_pack = (uint4*)ws;
  uint4* Wih_pack = (uint4*)(ws + 524288);
  uint4* Wa_pack = (uint4*)(ws + 1048576);
  unsigned long long* ywp = (unsigned long long*)(ws + 1310720);
  unsigned long long* psx = (unsigned long long*)(ws + 1835008);

  pack_weights<<<256, 256, 0, stream>>>(W_ih, W_hh, W_a, Whh_pack, Wih_pack, Wa_pack, ywp,
                                        psx);
  alstm_rec<<<256, 512, 0, stream>>>(lens, embs, Whh_pack, Wih_pack, Wa_pack, b_ih, b_hh, b_a,
                                     ywp, psx, out, hfin, cfin);
}